// Round 8
// baseline (428.512 us; speedup 1.0000x reference)
//
#include <hip/hip_runtime.h>
#include <stdint.h>

#define BATCH 16
#define CH    256
#define CQ    32
#define NPIX  4096
#define WROWS 320

typedef float f32x4 __attribute__((ext_vector_type(4)));
typedef short s16x8 __attribute__((ext_vector_type(8)));

__device__ __forceinline__ ushort f2bf(float f){
  union { float f; uint32_t u; } a; a.f = f;
  uint32_t r = a.u + 0x7FFFu + ((a.u >> 16) & 1u);
  return (ushort)(r >> 16);
}
__device__ __forceinline__ float bf2f(ushort h){
  union { float f; uint32_t u; } a; a.u = ((uint32_t)h) << 16; return a.f;
}
__device__ __forceinline__ void gload16(const void* g, void* l){
  __builtin_amdgcn_global_load_lds(
      (const __attribute__((address_space(1))) uint32_t*)g,
      (__attribute__((address_space(3))) uint32_t*)l, 16, 0, 0);
}

// ------------------------------------------------------------------
// prep_w: W (fp32) -> bf16 hi/lo planes [320][256]. (unchanged)
// ------------------------------------------------------------------
__global__ __launch_bounds__(256) void prep_w(
    const float* __restrict__ Wq, const float* __restrict__ Wk,
    const float* __restrict__ Wv,
    ushort* __restrict__ whi, ushort* __restrict__ wlo)
{
  int idx = blockIdx.x*256 + threadIdx.x;
  int r = idx >> 8;
  float f = (r < 32) ? Wq[idx] : (r < 64) ? Wk[idx - 32*CH] : Wv[idx - 64*CH];
  ushort h = f2bf(f);
  whi[idx] = h;
  wlo[idx] = f2bf(f - bf2f(h));
}

// ------------------------------------------------------------------
// proj_mfma: q/k/v = W @ x + b, bf16 MFMA, 3-term hi/lo. (unchanged)
// ------------------------------------------------------------------
__global__ __launch_bounds__(256,2) void proj_mfma(
    const float* __restrict__ x,
    const ushort* __restrict__ whi, const ushort* __restrict__ wlo,
    const float* __restrict__ bq, const float* __restrict__ bk,
    const float* __restrict__ bv,
    ushort* __restrict__ qhi, ushort* __restrict__ qlo,
    ushort* __restrict__ khi, ushort* __restrict__ klo,
    ushort* __restrict__ vt)
{
  __shared__ __align__(16) float xT[64*256];
  const int b  = blockIdx.y;
  const int n0 = blockIdx.x * 64;
  const int t  = threadIdx.x;
  const int wu = __builtin_amdgcn_readfirstlane(t >> 6);
  const int l  = t & 63;
  const int g  = l >> 4, li = l & 15, lsw = l & 7;

  {
    const float* xb = x + ((size_t)b*CH)*NPIX + n0 + l;
    #pragma unroll
    for (int cq = 0; cq < 16; ++cq) {
      int c4 = wu*64 + cq*4;
      f32x4 v;
      v[0] = xb[(size_t)(c4+0)*NPIX];
      v[1] = xb[(size_t)(c4+1)*NPIX];
      v[2] = xb[(size_t)(c4+2)*NPIX];
      v[3] = xb[(size_t)(c4+3)*NPIX];
      int phys = (c4 >> 2) ^ lsw;
      *(f32x4*)&xT[l*256 + phys*4] = v;
    }
  }
  __syncthreads();

  f32x4 acc[5][4];
  #pragma unroll
  for (int ct=0;ct<5;++ct)
    #pragma unroll
    for (int nt=0;nt<4;++nt) acc[ct][nt] = (f32x4){0.f,0.f,0.f,0.f};

  #pragma unroll 1
  for (int ks = 0; ks < 8; ++ks) {
    s16x8 wh[5], wl[5];
    #pragma unroll
    for (int ct = 0; ct < 5; ++ct) {
      size_t off = (size_t)(wu*80 + ct*16 + li)*CH + ks*32 + g*8;
      wh[ct] = *(const s16x8*)(whi + off);
      wl[ct] = *(const s16x8*)(wlo + off);
    }
    s16x8 xh[4], xl[4];
    #pragma unroll
    for (int nt = 0; nt < 4; ++nt) {
      int row = nt*16 + li;
      int ch0 = ks*8 + 2*g;
      f32x4 a0 = *(const f32x4*)&xT[row*256 + ((ch0    ) ^ (li&7))*4];
      f32x4 a1 = *(const f32x4*)&xT[row*256 + ((ch0 + 1) ^ (li&7))*4];
      float fv[8] = {a0[0],a0[1],a0[2],a0[3],a1[0],a1[1],a1[2],a1[3]};
      union { ushort u[8]; s16x8 v; } ph, pl;
      #pragma unroll
      for (int e=0;e<8;++e){
        ushort h = f2bf(fv[e]); ph.u[e] = h; pl.u[e] = f2bf(fv[e] - bf2f(h));
      }
      xh[nt] = ph.v; xl[nt] = pl.v;
    }
    #pragma unroll
    for (int ct=0;ct<5;++ct)
      #pragma unroll
      for (int nt=0;nt<4;++nt){
        acc[ct][nt] = __builtin_amdgcn_mfma_f32_16x16x32_bf16(wh[ct], xh[nt], acc[ct][nt], 0,0,0);
        acc[ct][nt] = __builtin_amdgcn_mfma_f32_16x16x32_bf16(wh[ct], xl[nt], acc[ct][nt], 0,0,0);
        acc[ct][nt] = __builtin_amdgcn_mfma_f32_16x16x32_bf16(wl[ct], xh[nt], acc[ct][nt], 0,0,0);
      }
  }

  const int rsub = g*4;
  #pragma unroll
  for (int ct = 0; ct < 5; ++ct) {
    const int cog = wu*80 + ct*16;
    if (cog < 64) {
      const float*  bias = (cog < 32) ? bq  : bk;
      ushort*       dhi  = (cog < 32) ? qhi : khi;
      ushort*       dlo  = (cog < 32) ? qlo : klo;
      const int cb = (cog & 31) + rsub;
      float4 bi = *(const float4*)(bias + cb);
      #pragma unroll
      for (int nt = 0; nt < 4; ++nt) {
        int n = n0 + nt*16 + li;
        union { ushort u[4]; uint2 v; } ph, pl;
        #pragma unroll
        for (int r = 0; r < 4; ++r) {
          float val = acc[ct][nt][r] + ((const float*)&bi)[r];
          ushort h = f2bf(val);
          ph.u[r] = h; pl.u[r] = f2bf(val - bf2f(h));
        }
        size_t base = ((size_t)b*NPIX + n)*CQ + cb;
        *(uint2*)(dhi + base) = ph.v;
        *(uint2*)(dlo + base) = pl.v;
      }
    } else {
      const int vr = cog - 64 + rsub;
      float4 bi = *(const float4*)(bv + vr);
      #pragma unroll
      for (int nt = 0; nt < 4; ++nt) {
        int n = n0 + nt*16 + li;
        #pragma unroll
        for (int r = 0; r < 4; ++r)
          vt[((size_t)b*CH + vr + r)*NPIX + n] =
              f2bf(acc[ct][nt][r] + ((const float*)&bi)[r]);
      }
    }
  }
}

// ------------------------------------------------------------------
// Fused flash attention + residual — occupancy restructure.
// QBLK=64 (4 waves x 16 i), KVBLK=32, LDS 36KB, 3 blocks/CU target.
// 128 j-tiles/block. Swapped MFMAs; swizzle keys &3, matched involutions.
// ------------------------------------------------------------------
__global__ __launch_bounds__(256,3) void attn_kernel(
    const ushort* __restrict__ qhi, const ushort* __restrict__ qlo,
    const ushort* __restrict__ khi, const ushort* __restrict__ klo,
    const ushort* __restrict__ vt,  const float* __restrict__ x,
    const float* __restrict__ gamma, float* __restrict__ out)
{
  __shared__ __align__(16) ushort vtile[2][CH*32];  // 32 KB dbuf
  __shared__ __align__(16) ushort ptile[4][16*32];  // 4 KB, wave-private

  const int flat = blockIdx.x + (int)gridDim.x * blockIdx.y;  // 0..1023
  const int nf   = (flat & 7)*128 + (flat >> 3);              // bijective
  const int b    = nf >> 6;
  const int i0   = (nf & 63) << 6;

  const int t   = threadIdx.x;
  const int wu  = __builtin_amdgcn_readfirstlane(t >> 6);
  const int l   = t & 63, lhi = l >> 4, llo = l & 15;

  const int crow = l >> 2;                 // 0..15
  const int jsw  = ((l & 3) ^ (crow & 3)) * 8;
  const uint32_t vbase = (uint32_t)((b*CH + wu*64 + crow)*NPIX) + (uint32_t)jsw;

  s16x8 qh, qlf;
  {
    size_t off = ((size_t)b*NPIX + i0 + wu*16 + llo)*CQ + lhi*8;
    qh  = *(const s16x8*)(qhi + off);
    qlf = *(const s16x8*)(qlo + off);
  }

  f32x4 acc[16];
  #pragma unroll
  for (int ct=0;ct<16;++ct) acc[ct] = (f32x4){0.f,0.f,0.f,0.f};
  float m = -1e30f, ls = 0.f;

  ushort* pt = ptile[wu];
  const ushort* kbh = khi + (size_t)b*NPIX*CQ;
  const ushort* kbl = klo + (size_t)b*NPIX*CQ;
  const int kofs_lane = llo*CQ + lhi*8;

  #pragma unroll
  for (int k=0;k<4;++k)
    gload16(vt + vbase + (uint32_t)(k*16*NPIX), &vtile[0][(wu*64 + k*16)*32]);
  __syncthreads();

  #pragma unroll 1
  for (int tt=0; tt<128; ++tt){
    const int cur = tt & 1;

    s16x8 kh[2], kl2[2];
    #pragma unroll
    for (int jt=0;jt<2;++jt){
      int ko = (tt*32 + jt*16)*CQ + kofs_lane;
      kh[jt]  = *(const s16x8*)(kbh + ko);
      kl2[jt] = *(const s16x8*)(kbl + ko);
    }
    __builtin_amdgcn_sched_barrier(0);
    if (tt < 127){
      const uint32_t src = vbase + (uint32_t)((tt+1)*32);
      #pragma unroll
      for (int k=0;k<4;++k)
        gload16(vt + src + (uint32_t)(k*16*NPIX),
                &vtile[cur^1][(wu*64 + k*16)*32]);
    }

    f32x4 st[2];
    st[0] = (f32x4){0.f,0.f,0.f,0.f};
    st[1] = (f32x4){0.f,0.f,0.f,0.f};
    __builtin_amdgcn_s_setprio(1);
    #pragma unroll
    for (int jt=0;jt<2;++jt){
      st[jt] = __builtin_amdgcn_mfma_f32_16x16x32_bf16(kh[jt],  qh,  st[jt], 0,0,0);
      st[jt] = __builtin_amdgcn_mfma_f32_16x16x32_bf16(kl2[jt], qh,  st[jt], 0,0,0);
      st[jt] = __builtin_amdgcn_mfma_f32_16x16x32_bf16(kh[jt],  qlf, st[jt], 0,0,0);
    }
    __builtin_amdgcn_s_setprio(0);

    float mt = st[0][0];
    #pragma unroll
    for (int jt=0;jt<2;++jt)
      #pragma unroll
      for (int r=0;r<4;++r) mt = fmaxf(mt, st[jt][r]);
    mt = fmaxf(mt, __shfl_xor(mt, 16)); mt = fmaxf(mt, __shfl_xor(mt, 32));
    int keep = (mt <= m + 8.f);                 // defer-max (T13)
    if (!__all(keep)){
      float nm = fmaxf(m, mt);
      float f = __expf(m - nm);
      m = nm; ls *= f;
      #pragma unroll
      for (int ct=0;ct<16;++ct) acc[ct] *= f;
    }
    {
      float lacc = 0.f;
      #pragma unroll
      for (int jt=0;jt<2;++jt){
        union { ushort u[4]; uint2 v; } pk;
        #pragma unroll
        for (int r=0;r<4;++r){
          float p = __expf(st[jt][r] - m);
          lacc += p;
          pk.u[r] = f2bf(p);
        }
        int jcb = jt*2 + (lhi>>1);
        int sub = lhi & 1;
        *(uint2*)&pt[llo*32 + ((jcb ^ (llo&3))<<3) + sub*4] = pk.v;
      }
      ls += lacc;
    }
    s16x8 pf = *(const s16x8*)&pt[llo*32 + ((lhi ^ (llo&3))<<3)];
    __builtin_amdgcn_s_setprio(1);
    #pragma unroll
    for (int ct=0; ct<16; ++ct){
      int c = ct*16 + llo;
      s16x8 vf = *(const s16x8*)&vtile[cur][c*32 + ((lhi ^ (c&3))<<3)];
      acc[ct] = __builtin_amdgcn_mfma_f32_16x16x32_bf16(vf, pf, acc[ct], 0,0,0);
    }
    __builtin_amdgcn_s_setprio(0);
    __syncthreads();
  }

  ls += __shfl_xor(ls,16); ls += __shfl_xor(ls,32);
  float rinv = 1.f/ls;
  float gmv = gamma[0];
  #pragma unroll
  for (int ct=0; ct<16; ++ct){
    #pragma unroll
    for (int r=0;r<4;++r){
      int c  = ct*16 + lhi*4 + r;
      int ii = i0 + wu*16 + llo;
      size_t o = ((size_t)b*CH + c)*NPIX + ii;
      out[o] = gmv * acc[ct][r] * rinv + x[o];
    }
  }
}

extern "C" void kernel_launch(void* const* d_in, const int* in_sizes, int n_in,
                              void* d_out, int out_size, void* d_ws, size_t ws_size,
                              hipStream_t stream)
{
  (void)in_sizes; (void)n_in; (void)out_size; (void)ws_size;
  const float* x     = (const float*)d_in[0];
  const float* Wq    = (const float*)d_in[1];
  const float* bq    = (const float*)d_in[2];
  const float* Wk    = (const float*)d_in[3];
  const float* bk    = (const float*)d_in[4];
  const float* Wv    = (const float*)d_in[5];
  const float* bv    = (const float*)d_in[6];
  const float* gamma = (const float*)d_in[7];
  float* out = (float*)d_out;

  ushort* ws = (ushort*)d_ws;
  const size_t qk_elems = (size_t)BATCH*NPIX*CQ;
  ushort* qhi = ws;
  ushort* qlo = qhi + qk_elems;
  ushort* khi = qlo + qk_elems;
  ushort* klo = khi + qk_elems;
  ushort* vt  = klo + qk_elems;
  ushort* whi = vt  + (size_t)BATCH*CH*NPIX;
  ushort* wlo = whi + (size_t)WROWS*CH;

  prep_w<<<dim3(WROWS), dim3(256), 0, stream>>>(Wq, Wk, Wv, whi, wlo);
  dim3 gp(64, BATCH);
  proj_mfma<<<gp, dim3(256), 0, stream>>>(x, whi, wlo, bq, bk, bv,
                                          qhi, qlo, khi, klo, vt);
  dim3 ga(64, BATCH);
  attn_kernel<<<ga, dim3(256), 0, stream>>>(qhi, qlo, khi, klo, vt, x, gamma, out);
}